// Round 5
// baseline (326.084 us; speedup 1.0000x reference)
//
#include <hip/hip_runtime.h>

// ---------------------------------------------------------------------------
// UnidirectionalAttn: B=4, S=2048, HIDDEN=1024, NH=16, HEAD=64
// prep(bf16, +pos) -> W transpose -> QKV GEMM (global_load_lds + XOR-swizzle)
// -> flash attn split-KV (swizzled LDS, reg-prefetch dbuf, additive no-max
// partials) -> merge -> out GEMM (global_load_lds + XOR-swizzle).
// ---------------------------------------------------------------------------

typedef float f32x4 __attribute__((ext_vector_type(4)));
typedef short bf16x8 __attribute__((ext_vector_type(8)));   // 8 bf16 = 4 VGPRs
typedef short bf16x4 __attribute__((ext_vector_type(4)));   // 4 bf16 = 2 VGPRs

#define MFMA_BF16(a, b, c) __builtin_amdgcn_mfma_f32_16x16x32_bf16((a), (b), (c), 0, 0, 0)

#if __has_builtin(__builtin_amdgcn_mfma_f32_16x16x16bf16_1k)
#define HAVE_MFMA16 1
#define MFMA_BF16_K16(a, b, c) __builtin_amdgcn_mfma_f32_16x16x16bf16_1k((a), (b), (c), 0, 0, 0)
#else
#define HAVE_MFMA16 0
#endif

// async 16B/lane global->LDS DMA. lds must be wave-uniform; HW adds lane*16.
#define ASYNC_COPY16(lds, g)                                                   \
  __builtin_amdgcn_global_load_lds(                                            \
      (const __attribute__((address_space(1))) void*)(g),                      \
      (__attribute__((address_space(3))) void*)(lds), 16, 0, 0)

__device__ __forceinline__ short f2bf(float f) {
  union { float f; unsigned u; } v; v.f = f;
  unsigned u = v.u;
  u += 0x7fffu + ((u >> 16) & 1u);   // round-to-nearest-even
  return (short)(u >> 16);
}

__device__ __forceinline__ float bf2f(short s) {
  union { unsigned u; float f; } v;
  v.u = ((unsigned)(unsigned short)s) << 16;
  return v.f;
}

__device__ __forceinline__ int pack_bf2_fast(float a, float b) {
  union { float f; unsigned u; } va, vb; va.f = a; vb.f = b;
  unsigned ua = va.u + 0x8000u;      // round-half-up (P matrix: bias negligible)
  unsigned ub = vb.u + 0x8000u;
  return (int)((ua >> 16) | (ub & 0xffff0000u));
}

// split-KV chunk tables: chunk = 12 KV tiles (768 kv). Per qt: nch=ceil((2qt+2)/12).
__device__ const int QT_X[30] = {5,6,7,8,9,10,11,11,12,12,13,13,14,14,15,15,
                                 4,10, 3,9,15, 2,8,14, 1,7,13, 0,6,12};
__device__ const int CH_X[30] = {0,0,0,0,0,0,0,1,0,1,0,1,0,1,0,1,
                                 0,1, 0,1,2, 0,1,2, 0,1,2, 0,1,2};
__device__ const int START_QT[16] = {0,1,2,3,4,5,6,8,10,12,14,16,18,21,24,27};

// ---------------------------------------------------------------------------
// Kernel 1: xb = bf16(x), xpb = bf16(x + pos)
// ---------------------------------------------------------------------------
__global__ __launch_bounds__(256) void prep_x(const float* __restrict__ x,
                                              const float* __restrict__ pos,
                                              short* __restrict__ xb,
                                              short* __restrict__ xpb) {
  int i = blockIdx.x * 256 + threadIdx.x;
  int idx = i * 4;
  const float4 xv = *(const float4*)(x + idx);
  const float4 pv = *(const float4*)(pos + (idx & ((2048 * 1024) - 1)));
  short4 a, b;
  a.x = f2bf(xv.x); a.y = f2bf(xv.y); a.z = f2bf(xv.z); a.w = f2bf(xv.w);
  b.x = f2bf(xv.x + pv.x); b.y = f2bf(xv.y + pv.y);
  b.z = f2bf(xv.z + pv.z); b.w = f2bf(xv.w + pv.w);
  *(short4*)(xb + idx) = a;
  *(short4*)(xpb + idx) = b;
}

// ---------------------------------------------------------------------------
// Kernel 2: W [K][N] f32 -> W^T [N][K] bf16
// ---------------------------------------------------------------------------
__global__ __launch_bounds__(256) void transpose_w(const float* __restrict__ in,
                                                   short* __restrict__ out,
                                                   int K, int N) {
  __shared__ float tile[32][33];
  int n0 = blockIdx.x * 32, k0 = blockIdx.y * 32;
  int c = threadIdx.x & 31, r0 = threadIdx.x >> 5;
  for (int i = 0; i < 4; i++) {
    int r = r0 + i * 8;
    tile[r][c] = in[(size_t)(k0 + r) * N + n0 + c];
  }
  __syncthreads();
  for (int i = 0; i < 4; i++) {
    int r = r0 + i * 8;
    out[(size_t)(n0 + r) * K + k0 + c] = f2bf(tile[c][r]);
  }
}

// ---------------------------------------------------------------------------
// Kernel 3: QKV GEMM, m97-style: 128x128 tile, BK=64, global_load_lds(16B)
// staging into XOR-swizzled pitch-64 LDS (group g at position g^(row&7)).
// q pre-scaled by log2(e)/8 (exp2 softmax).
// ---------------------------------------------------------------------------
__global__ __launch_bounds__(256) void gemm_qkv(const short* __restrict__ xb,
                                                const short* __restrict__ xpb,
                                                const short* __restrict__ wt,
                                                short* __restrict__ qg,
                                                short* __restrict__ kg,
                                                short* __restrict__ vtg) {
  __shared__ __align__(16) short As[128 * 64];   // 16 KB, swizzled
  __shared__ __align__(16) short Bs[128 * 64];
  const int bm = blockIdx.x, bn = blockIdx.y;
  const short* __restrict__ A = (bn < 16) ? xpb : xb;
  const int tid = threadIdx.x;
  const int lane = tid & 63, w = tid >> 6;
  const int wm = w & 1, wn = w >> 1;
  const int quad = lane >> 4, l16 = lane & 15;
  const f32x4 fzero = {0.f, 0.f, 0.f, 0.f};
  f32x4 acc[4][4];
  for (int mt = 0; mt < 4; mt++)
    for (int nt = 0; nt < 4; nt++) acc[mt][nt] = fzero;
  const int arow0 = bm * 128, brow0 = bn * 128;
  // per-lane DMA source: row = base + w*32 + i*8 + (lane>>3); swizzled col
  // (row&7 == lane>>3 for all i, so swizzle is lane-constant)
  const int swz8 = ((lane & 7) ^ (lane >> 3)) * 8;
  const short* gA = A + (size_t)(arow0 + w * 32 + (lane >> 3)) * 1024 + swz8;
  const short* gB = wt + (size_t)(brow0 + w * 32 + (lane >> 3)) * 1024 + swz8;
  char* ldsA = (char*)As + w * 4096;
  char* ldsB = (char*)Bs + w * 4096;

  for (int k0 = 0; k0 < 1024; k0 += 64) {
#pragma unroll
    for (int i = 0; i < 4; i++) {
      ASYNC_COPY16(ldsA + i * 1024, gA + i * 8192 + k0);
      ASYNC_COPY16(ldsB + i * 1024, gB + i * 8192 + k0);
    }
    __syncthreads();
#pragma unroll
    for (int ks = 0; ks < 2; ks++) {
      bf16x8 af[4], bfr[4];
#pragma unroll
      for (int mt = 0; mt < 4; mt++)
        af[mt] = *(const bf16x8*)(As + (wm * 64 + mt * 16 + l16) * 64 +
                                  (((ks * 4 + quad) ^ (l16 & 7)) * 8));
#pragma unroll
      for (int nt = 0; nt < 4; nt++)
        bfr[nt] = *(const bf16x8*)(Bs + (wn * 64 + nt * 16 + l16) * 64 +
                                   (((ks * 4 + quad) ^ (l16 & 7)) * 8));
#pragma unroll
      for (int mt = 0; mt < 4; mt++)
#pragma unroll
        for (int nt = 0; nt < 4; nt++)
          acc[mt][nt] = MFMA_BF16(af[mt], bfr[nt], acc[mt][nt]);
    }
    __syncthreads();
  }
  for (int nt = 0; nt < 4; nt++) {
    int col = bn * 128 + wn * 64 + nt * 16 + l16;
    int kk = col >> 10, head = (col >> 6) & 15, hh = col & 63;
    for (int mt = 0; mt < 4; mt++) {
      int rowb = bm * 128 + wm * 64 + mt * 16 + quad * 4;
      int b = rowb >> 11, s0 = rowb & 2047;
      if (kk == 2) {
        short4 sv;
        sv.x = f2bf(acc[mt][nt][0]); sv.y = f2bf(acc[mt][nt][1]);
        sv.z = f2bf(acc[mt][nt][2]); sv.w = f2bf(acc[mt][nt][3]);
        *(short4*)(vtg + (size_t)((b * 16 + head) * 64 + hh) * 2048 + s0) = sv;
      } else {
        short* __restrict__ dst = (kk == 0) ? qg : kg;
        float scale = (kk == 0) ? 0.18033688f : 1.0f;   // 1/8 * log2(e)
        for (int r = 0; r < 4; r++)
          dst[(size_t)((b * 16 + head) * 2048 + s0 + r) * 64 + hh] =
              f2bf(acc[mt][nt][r] * scale);
      }
    }
  }
}

// ---------------------------------------------------------------------------
// Kernel 4a: flash attention partials. Block = (bh, qt, kv-chunk<=12 tiles).
// S^T form, reg-prefetch dbuf, XOR-swizzled pitch-64 LDS, no-max exp2 softmax.
// Writes additive partials: unnormalized O^T (bf16) + l (f32).
// ---------------------------------------------------------------------------
__global__ __launch_bounds__(256, 4) void attn_part(const short* __restrict__ qg,
                                                    const short* __restrict__ kg,
                                                    const short* __restrict__ vtg,
                                                    short* __restrict__ pO,
                                                    float* __restrict__ pL) {
  const int xi = blockIdx.x;
  const int qt = QT_X[xi], ch = CH_X[xi];
  const int head = blockIdx.y, b = blockIdx.z;
  const int bh = b * 16 + head;
  const int p = bh * 30 + START_QT[qt] + ch;
  const short* __restrict__ Q = qg + (size_t)bh * 2048 * 64;
  const short* __restrict__ K = kg + (size_t)bh * 2048 * 64;
  const short* __restrict__ VT = vtg + (size_t)bh * 64 * 2048;
  __shared__ __align__(16) short Ks[2][64 * 64];   // swizzled, 8 KB each
  __shared__ __align__(16) short Vs[2][64 * 64];
#if !HAVE_MFMA16
  __shared__ __align__(16) short Ps[4][16 * 72];
#endif
  const int tid = threadIdx.x, lane = tid & 63, w = tid >> 6;
  const int quad = lane >> 4, l16 = lane & 15;
  const f32x4 fzero = {0.f, 0.f, 0.f, 0.f};

  // Q B-frags (16x16x32): lane holds Q[q=l16][h=ks*32+quad*8+j]
  bf16x8 bq[2][2];
#pragma unroll
  for (int sub = 0; sub < 2; sub++) {
    int qrow = qt * 128 + w * 32 + sub * 16 + l16;
#pragma unroll
    for (int ks = 0; ks < 2; ks++)
      bq[sub][ks] = *(const bf16x8*)(Q + (size_t)qrow * 64 + ks * 32 + quad * 8);
  }
  f32x4 acco[2][4];
  f32x4 lrun[2];
#pragma unroll
  for (int sub = 0; sub < 2; sub++) {
    for (int nt = 0; nt < 4; nt++) acco[sub][nt] = fzero;
    lrun[sub] = fzero;
  }

  const int kt0 = ch * 12;
  const int kt1 = min(kt0 + 12, 2 * qt + 2);   // exclusive
  const int qmin_w = qt * 128 + w * 32;

  // staging: thread covers chunks c = tid (row sr0) and tid+256 (row 32+sr0)
  const int sr0 = tid >> 3;
  const int sc0 = (tid & 7) * 8;                       // logical col (global)
  const int swz = (((tid & 7) ^ (sr0 & 7)) * 8);       // swizzled col (LDS)
  const int o0 = sr0 * 64 + swz, o1 = (32 + sr0) * 64 + swz;

  int4 kreg[2], vreg[2];
  {
    int kv0 = kt0 * 64;
    kreg[0] = *(const int4*)(K + (size_t)(kv0 + sr0) * 64 + sc0);
    kreg[1] = *(const int4*)(K + (size_t)(kv0 + 32 + sr0) * 64 + sc0);
    vreg[0] = *(const int4*)(VT + (size_t)sr0 * 2048 + kv0 + sc0);
    vreg[1] = *(const int4*)(VT + (size_t)(32 + sr0) * 2048 + kv0 + sc0);
    *(int4*)(&Ks[0][o0]) = kreg[0];
    *(int4*)(&Ks[0][o1]) = kreg[1];
    *(int4*)(&Vs[0][o0]) = vreg[0];
    *(int4*)(&Vs[0][o1]) = vreg[1];
  }
  __syncthreads();

  for (int kt = kt0; kt < kt1; kt++) {
    const int cur = (kt - kt0) & 1;
    if (kt + 1 < kt1) {
      int kv0 = (kt + 1) * 64;
      kreg[0] = *(const int4*)(K + (size_t)(kv0 + sr0) * 64 + sc0);
      kreg[1] = *(const int4*)(K + (size_t)(kv0 + 32 + sr0) * 64 + sc0);
      vreg[0] = *(const int4*)(VT + (size_t)sr0 * 2048 + kv0 + sc0);
      vreg[1] = *(const int4*)(VT + (size_t)(32 + sr0) * 2048 + kv0 + sc0);
    }

    if (kt * 64 <= qmin_w + 31) {
      f32x4 accs[2][4];
#pragma unroll
      for (int sub = 0; sub < 2; sub++)
        for (int nt = 0; nt < 4; nt++) accs[sub][nt] = fzero;
#pragma unroll
      for (int ks = 0; ks < 2; ks++)
#pragma unroll
        for (int nt = 0; nt < 4; nt++) {
          bf16x8 ak = *(const bf16x8*)(&Ks[cur][(nt * 16 + l16) * 64 +
                                               (((ks * 4 + quad) ^ (l16 & 7)) * 8)]);
          accs[0][nt] = MFMA_BF16(ak, bq[0][ks], accs[0][nt]);
          accs[1][nt] = MFMA_BF16(ak, bq[1][ks], accs[1][nt]);
        }

      if ((kt + 1) * 64 > qmin_w) {        // partial-mask tile
#pragma unroll
        for (int sub = 0; sub < 2; sub++) {
          int q = qmin_w + sub * 16 + l16;
#pragma unroll
          for (int nt = 0; nt < 4; nt++) {
            int kv = kt * 64 + nt * 16 + quad * 4;
#pragma unroll
            for (int r = 0; r < 4; r++)
              if (kv + r > q) accs[sub][nt][r] = -1e30f;
          }
        }
      }

      // no-max softmax (scores in log2 units)
#pragma unroll
      for (int sub = 0; sub < 2; sub++)
#pragma unroll
        for (int nt = 0; nt < 4; nt++) {
#pragma unroll
          for (int r = 0; r < 4; r++) accs[sub][nt][r] = exp2f(accs[sub][nt][r]);
          lrun[sub] += accs[sub][nt];
        }

#if HAVE_MFMA16
      // C-layout of accs == B-frag layout of 16x16x16 (B[k=quad*4+j][n=l16])
#pragma unroll
      for (int kk = 0; kk < 4; kk++) {
        union { int2 i2; bf16x4 v; } p0, p1;
        p0.i2.x = pack_bf2_fast(accs[0][kk][0], accs[0][kk][1]);
        p0.i2.y = pack_bf2_fast(accs[0][kk][2], accs[0][kk][3]);
        p1.i2.x = pack_bf2_fast(accs[1][kk][0], accs[1][kk][1]);
        p1.i2.y = pack_bf2_fast(accs[1][kk][2], accs[1][kk][3]);
#pragma unroll
        for (int nth = 0; nth < 4; nth++) {
          bf16x4 av = *(const bf16x4*)(&Vs[cur][(nth * 16 + l16) * 64 +
                                               (((kk * 2 + (quad >> 1)) ^ (l16 & 7)) * 8) +
                                               (quad & 1) * 4]);
          acco[0][nth] = MFMA_BF16_K16(av, p0.v, acco[0][nth]);
          acco[1][nth] = MFMA_BF16_K16(av, p1.v, acco[1][nth]);
        }
      }
#else
      short* P = Ps[w];
#pragma unroll
      for (int sub = 0; sub < 2; sub++) {
#pragma unroll
        for (int nt = 0; nt < 4; nt++) {
          int2 pk;
          pk.x = pack_bf2_fast(accs[sub][nt][0], accs[sub][nt][1]);
          pk.y = pack_bf2_fast(accs[sub][nt][2], accs[sub][nt][3]);
          *(int2*)(P + l16 * 72 + nt * 16 + quad * 4) = pk;
        }
#pragma unroll
        for (int ks2 = 0; ks2 < 2; ks2++) {
          bf16x8 bp = *(const bf16x8*)(P + l16 * 72 + ks2 * 32 + quad * 8);
#pragma unroll
          for (int nth = 0; nth < 4; nth++) {
            bf16x8 av = *(const bf16x8*)(&Vs[cur][(nth * 16 + l16) * 64 +
                                                 (((ks2 * 4 + quad) ^ (l16 & 7)) * 8)]);
            acco[sub][nth] = MFMA_BF16(av, bp, acco[sub][nth]);
          }
        }
      }
#endif
    }

    if (kt + 1 < kt1) {
      const int nxt = cur ^ 1;
      *(int4*)(&Ks[nxt][o0]) = kreg[0];
      *(int4*)(&Ks[nxt][o1]) = kreg[1];
      *(int4*)(&Vs[nxt][o0]) = vreg[0];
      *(int4*)(&Vs[nxt][o1]) = vreg[1];
    }
    __syncthreads();
  }

  // write partials (unnormalized O^T as [q][h] bf16, l per q row)
#pragma unroll
  for (int sub = 0; sub < 2; sub++) {
    float lh = (lrun[sub][0] + lrun[sub][1]) + (lrun[sub][2] + lrun[sub][3]);
    lh += __shfl_xor(lh, 16);
    lh += __shfl_xor(lh, 32);
    int qloc = w * 32 + sub * 16 + l16;
    if (quad == 0) pL[p * 128 + qloc] = lh;
    size_t base = (size_t)p * 8192 + (size_t)qloc * 64;
#pragma unroll
    for (int nth = 0; nth < 4; nth++) {
      short4 sv;
      sv.x = f2bf(acco[sub][nth][0]);
      sv.y = f2bf(acco[sub][nth][1]);
      sv.z = f2bf(acco[sub][nth][2]);
      sv.w = f2bf(acco[sub][nth][3]);
      *(short4*)(pO + base + nth * 16 + quad * 4) = sv;
    }
  }
}

// ---------------------------------------------------------------------------
// Kernel 4b: merge partials -> comb (bf16). Block = (qt, head, b).
// ---------------------------------------------------------------------------
__global__ __launch_bounds__(256) void attn_merge(const short* __restrict__ pO,
                                                  const float* __restrict__ pL,
                                                  short* __restrict__ comb) {
  const int qt = blockIdx.x, head = blockIdx.y, b = blockIdx.z;
  const int bh = b * 16 + head;
  const int nch = (2 * qt + 13) / 12;      // ceil((2qt+2)/12), 1..3
  const int p0 = bh * 30 + START_QT[qt];
  const int t = threadIdx.x;
  const int qloc = t >> 1, hh = (t & 1) * 32;

  float l = 0.f;
  for (int c = 0; c < nch; c++) l += pL[(p0 + c) * 128 + qloc];
  const float inv = 1.f / l;

  float acc[32];
#pragma unroll
  for (int j = 0; j < 32; j++) acc[j] = 0.f;
  for (int c = 0; c < nch; c++) {
    const short* src = pO + (size_t)(p0 + c) * 8192 + (size_t)qloc * 64 + hh;
#pragma unroll
    for (int v = 0; v < 4; v++) {
      short4 d0 = *(const short4*)(src + v * 8);
      short4 d1 = *(const short4*)(src + v * 8 + 4);
      acc[v * 8 + 0] += bf2f(d0.x); acc[v * 8 + 1] += bf2f(d0.y);
      acc[v * 8 + 2] += bf2f(d0.z); acc[v * 8 + 3] += bf2f(d0.w);
      acc[v * 8 + 4] += bf2f(d1.x); acc[v * 8 + 5] += bf2f(d1.y);
      acc[v * 8 + 6] += bf2f(d1.z); acc[v * 8 + 7] += bf2f(d1.w);
    }
  }
  size_t base = (size_t)(b * 2048 + qt * 128 + qloc) * 1024 + head * 64 + hh;
#pragma unroll
  for (int v = 0; v < 8; v++) {
    short4 sv;
    sv.x = f2bf(acc[v * 4 + 0] * inv);
    sv.y = f2bf(acc[v * 4 + 1] * inv);
    sv.z = f2bf(acc[v * 4 + 2] * inv);
    sv.w = f2bf(acc[v * 4 + 3] * inv);
    *(short4*)(comb + base + v * 4) = sv;
  }
}

// ---------------------------------------------------------------------------
// Kernel 5: out = comb @ Wo (fp32 stores), same m97-style staging
// ---------------------------------------------------------------------------
__global__ __launch_bounds__(256) void gemm_out(const short* __restrict__ A,
                                                const short* __restrict__ wt,
                                                float* __restrict__ out) {
  __shared__ __align__(16) short As[128 * 64];
  __shared__ __align__(16) short Bs[128 * 64];
  const int bm = blockIdx.x, bn = blockIdx.y;
  const int tid = threadIdx.x;
  const int lane = tid & 63, w = tid >> 6;
  const int wm = w & 1, wn = w >> 1;
  const int quad = lane >> 4, l16 = lane & 15;
  const f32x4 fzero = {0.f, 0.f, 0.f, 0.f};
  f32x4 acc[4][4];
  for (int mt = 0; mt < 4; mt++)
    for (int nt = 0; nt < 4; nt++) acc[mt][nt] = fzero;
  const int arow0 = bm * 128, brow0 = bn * 128;
  const int swz8 = ((lane & 7) ^ (lane >> 3)) * 8;
  const short* gA = A + (size_t)(arow0 + w * 32 + (lane >> 3)) * 1024 + swz8;
  const short* gB = wt + (size_t)(brow0 + w * 32 + (lane >> 3)) * 1024 + swz8;
  char* ldsA = (char*)As + w * 4096;
  char* ldsB = (char*)Bs + w * 4096;

  for (int k0 = 0; k0 < 1024; k0 += 64) {
#pragma unroll
    for (int i = 0; i < 4; i++) {
      ASYNC_COPY16(ldsA + i * 1024, gA + i * 8192 + k0);
      ASYNC_COPY16(ldsB + i * 1024, gB + i * 8192 + k0);
    }
    __syncthreads();
#pragma unroll
    for (int ks = 0; ks < 2; ks++) {
      bf16x8 af[4], bfr[4];
#pragma unroll
      for (int mt = 0; mt < 4; mt++)
        af[mt] = *(const bf16x8*)(As + (wm * 64 + mt * 16 + l16) * 64 +
                                  (((ks * 4 + quad) ^ (l16 & 7)) * 8));
#pragma unroll
      for (int nt = 0; nt < 4; nt++)
        bfr[nt] = *(const bf16x8*)(Bs + (wn * 64 + nt * 16 + l16) * 64 +
                                   (((ks * 4 + quad) ^ (l16 & 7)) * 8));
#pragma unroll
      for (int mt = 0; mt < 4; mt++)
#pragma unroll
        for (int nt = 0; nt < 4; nt++)
          acc[mt][nt] = MFMA_BF16(af[mt], bfr[nt], acc[mt][nt]);
    }
    __syncthreads();
  }
  for (int nt = 0; nt < 4; nt++) {
    int col = bn * 128 + wn * 64 + nt * 16 + l16;
    for (int mt = 0; mt < 4; mt++) {
      int rowb = bm * 128 + wm * 64 + mt * 16 + quad * 4;
      for (int r = 0; r < 4; r++)
        out[(size_t)(rowb + r) * 1024 + col] = acc[mt][nt][r];
    }
  }
}

// ---------------------------------------------------------------------------
extern "C" void kernel_launch(void* const* d_in, const int* in_sizes, int n_in,
                              void* d_out, int out_size, void* d_ws, size_t ws_size,
                              hipStream_t stream) {
  const float* x    = (const float*)d_in[0];
  const float* pos  = (const float*)d_in[1];
  const float* Wqkv = (const float*)d_in[2];
  const float* Wo   = (const float*)d_in[3];
  float* out = (float*)d_out;

  char* ws = (char*)d_ws;
  const size_t SZ = (size_t)8192 * 1024 * 2;
  // [0, 2*SZ): xb/xpb during prep+gemm_qkv, then recycled as attn partials.
  short* xb    = (short*)(ws);
  short* xpb   = (short*)(ws + SZ);
  short* pO    = (short*)(ws);                          // 1920*8192*2 = 31.5 MB
  float* pL    = (float*)(ws + (size_t)1920 * 8192 * 2); // 1920*128*4 = 0.98 MB
  short* q     = (short*)(ws + 2 * SZ);
  short* k     = (short*)(ws + 3 * SZ);
  short* vt    = (short*)(ws + 4 * SZ);
  short* comb  = (short*)(ws + 5 * SZ);
  short* wqkvt = (short*)(ws + 6 * SZ);
  short* wot   = (short*)(ws + 6 * SZ + (size_t)3072 * 1024 * 2);

  prep_x<<<8192, 256, 0, stream>>>(x, pos, xb, xpb);
  transpose_w<<<dim3(96, 32), 256, 0, stream>>>(Wqkv, wqkvt, 1024, 3072);
  transpose_w<<<dim3(32, 32), 256, 0, stream>>>(Wo, wot, 1024, 1024);
  gemm_qkv<<<dim3(64, 24), 256, 0, stream>>>(xb, xpb, wqkvt, q, k, vt);
  attn_part<<<dim3(30, 16, 4), 256, 0, stream>>>(q, k, vt, pO, pL);
  attn_merge<<<dim3(16, 16, 4), 256, 0, stream>>>(pO, pL, comb);
  gemm_out<<<dim3(64, 8), 256, 0, stream>>>(comb, wot, out);
}